// Round 1
// baseline (526.130 us; speedup 1.0000x reference)
//
#include <hip/hip_runtime.h>

// REGATConv on MI355X.
// Pipeline:
//   ws:  ft[N*256] fp32 | el[N*4] | er[N*4] | offsets[N+1] | cursor[N] | edge_by_dst[E]
//   K1 memset cursor=0
//   K2 histogram of dst
//   K3 single-block scan -> offsets (and cursor = start positions)
//   K4 scatter edge ids grouped by dst
//   K5 SGEMM ft = feat @ fc_w^T, fused el/er epilogue (wave shfl reductions)
//   K6 one wave per dst node: online softmax in registers + weighted gather of ft[src]

#define NF 256   // in feats
#define HD 256   // H*D
#define NH 4
#define DD 64

__global__ __launch_bounds__(256) void hist_k(const int* __restrict__ dst,
                                              int* __restrict__ cursor, int e) {
  int i = blockIdx.x * 256 + threadIdx.x;
  if (i < e) atomicAdd(&cursor[dst[i]], 1);
}

__global__ __launch_bounds__(1024) void scan_k(int* __restrict__ cursor,
                                               int* __restrict__ offs, int n) {
  __shared__ int wtot[16];
  __shared__ int wexcl[16];
  __shared__ int chunk_tot;
  __shared__ int carry_s;
  int tid = threadIdx.x, lane = tid & 63, wid = tid >> 6;
  if (tid == 0) carry_s = 0;
  __syncthreads();
  for (int base = 0; base < n; base += 1024) {
    int i = base + tid;
    int v = (i < n) ? cursor[i] : 0;
    int incl = v;
#pragma unroll
    for (int off = 1; off < 64; off <<= 1) {
      int t = __shfl_up(incl, off);
      if (lane >= off) incl += t;
    }
    if (lane == 63) wtot[wid] = incl;
    __syncthreads();
    if (wid == 0) {
      int w = (lane < 16) ? wtot[lane] : 0;
      int wi = w;
#pragma unroll
      for (int off = 1; off < 16; off <<= 1) {
        int t = __shfl_up(wi, off);
        if (lane >= off) wi += t;
      }
      if (lane < 16) wexcl[lane] = wi - w;
      if (lane == 15) chunk_tot = wi;
    }
    __syncthreads();
    int carry = carry_s;
    int excl = carry + wexcl[wid] + (incl - v);
    if (i < n) { offs[i] = excl; cursor[i] = excl; }
    __syncthreads();
    if (tid == 0) carry_s = carry + chunk_tot;
    __syncthreads();
  }
  if (tid == 0) offs[n] = carry_s;
}

__global__ __launch_bounds__(256) void scatter_k(const int* __restrict__ dst,
                                                 int* __restrict__ cursor,
                                                 int* __restrict__ ebd, int e) {
  int i = blockIdx.x * 256 + threadIdx.x;
  if (i < e) {
    int p = atomicAdd(&cursor[dst[i]], 1);
    ebd[p] = i;
  }
}

// SGEMM: ft[n][o] = sum_k feat[n][k] * fc_w[o][k]; BM=32, BN=256(all), BK=32.
// 256 threads: tx=tid&63 owns 4 cols (tx*4..), ty=tid>>6 owns 8 rows.
__global__ __launch_bounds__(256) void gemm_k(
    const float* __restrict__ feat, const float* __restrict__ fc_w,
    const float* __restrict__ attn_l, const float* __restrict__ attn_r,
    float* __restrict__ ft, float* __restrict__ el, float* __restrict__ er, int n) {
  __shared__ float As[32][36];    // [k][m], +4 pad keeps 16B alignment for b128 reads
  __shared__ float Bs[32][260];   // [k][c]
  int tid = threadIdx.x;
  int tx = tid & 63, ty = tid >> 6;
  int row0 = blockIdx.x * 32;
  int lrow = tid >> 3;            // 0..31
  int lk4 = (tid & 7) << 2;       // 0,4,..,28
  float acc[8][4];
#pragma unroll
  for (int i = 0; i < 8; ++i)
#pragma unroll
    for (int j = 0; j < 4; ++j) acc[i][j] = 0.f;

  int gr = row0 + lrow;
  if (gr >= n) gr = n - 1;
  const float* arow = feat + (size_t)gr * NF;

  for (int k0 = 0; k0 < NF; k0 += 32) {
    float4 av = *(const float4*)(arow + k0 + lk4);
    As[lk4 + 0][lrow] = av.x; As[lk4 + 1][lrow] = av.y;
    As[lk4 + 2][lrow] = av.z; As[lk4 + 3][lrow] = av.w;
#pragma unroll
    for (int g = 0; g < 8; ++g) {
      int c = lrow + (g << 5);
      float4 bv = *(const float4*)(fc_w + (size_t)c * NF + k0 + lk4);
      Bs[lk4 + 0][c] = bv.x; Bs[lk4 + 1][c] = bv.y;
      Bs[lk4 + 2][c] = bv.z; Bs[lk4 + 3][c] = bv.w;
    }
    __syncthreads();
#pragma unroll
    for (int k = 0; k < 32; ++k) {
      float4 b  = *(const float4*)&Bs[k][tx << 2];
      float4 a0 = *(const float4*)&As[k][ty << 3];
      float4 a1 = *(const float4*)&As[k][(ty << 3) + 4];
      float ar8[8] = {a0.x, a0.y, a0.z, a0.w, a1.x, a1.y, a1.z, a1.w};
#pragma unroll
      for (int i = 0; i < 8; ++i) {
        acc[i][0] = fmaf(ar8[i], b.x, acc[i][0]);
        acc[i][1] = fmaf(ar8[i], b.y, acc[i][1]);
        acc[i][2] = fmaf(ar8[i], b.z, acc[i][2]);
        acc[i][3] = fmaf(ar8[i], b.w, acc[i][3]);
      }
    }
    __syncthreads();
  }

  // epilogue: write ft tile + fused el/er (per-h wave reduction over 16-lane groups)
  float4 al  = *(const float4*)(attn_l + (tx << 2));
  float4 arr = *(const float4*)(attn_r + (tx << 2));
  int h = tx >> 4;
#pragma unroll
  for (int i = 0; i < 8; ++i) {
    int r = row0 + (ty << 3) + i;
    float pl = acc[i][0] * al.x + acc[i][1] * al.y + acc[i][2] * al.z + acc[i][3] * al.w;
    float pr = acc[i][0] * arr.x + acc[i][1] * arr.y + acc[i][2] * arr.z + acc[i][3] * arr.w;
#pragma unroll
    for (int off = 1; off <= 8; off <<= 1) {
      pl += __shfl_xor(pl, off);
      pr += __shfl_xor(pr, off);
    }
    if (r < n) {
      *(float4*)(ft + (size_t)r * HD + (tx << 2)) =
          make_float4(acc[i][0], acc[i][1], acc[i][2], acc[i][3]);
      if ((tx & 15) == 0) {
        el[r * NH + h] = pl;
        er[r * NH + h] = pr;
      }
    }
  }
}

// One wave per dst node. Online softmax in registers; serial edge loop for the
// weighted gather (lane = d, 4 heads per lane).
__global__ __launch_bounds__(256) void agg_k(
    const float* __restrict__ ft, const float* __restrict__ el,
    const float* __restrict__ er, const int* __restrict__ srcs,
    const int* __restrict__ efeats, const float* __restrict__ ewt,
    const int* __restrict__ offs, const int* __restrict__ ebd,
    float* __restrict__ out, int n) {
  __shared__ float ew_s[32];
  if (threadIdx.x < 32) {
    float w = ewt[threadIdx.x] * 100.0f;           // * ALPHA
    ew_s[threadIdx.x] = (w >= 0.f) ? w : 0.01f * w; // LeakyReLU(0.01)
  }
  __syncthreads();
  int node = blockIdx.x * 4 + (threadIdx.x >> 6);
  int lane = threadIdx.x & 63;
  if (node >= n) return;
  int start = offs[node];
  int deg = offs[node + 1] - start;
  float acc[4] = {0.f, 0.f, 0.f, 0.f};
  if (deg > 0) {
    float4 erv4 = *(const float4*)(er + (size_t)node * 4);
    float erv[4] = {erv4.x, erv4.y, erv4.z, erv4.w};
    float m[4] = {-1e30f, -1e30f, -1e30f, -1e30f};
    float s[4] = {0.f, 0.f, 0.f, 0.f};
    // pass A: per-lane online softmax over owned edges
    for (int i = lane; i < deg; i += 64) {
      int e = ebd[start + i];
      int sv = srcs[e];
      int et = efeats[e] - 1;
      float4 elv4 = *(const float4*)(el + (size_t)sv * 4);
      float elv[4] = {elv4.x, elv4.y, elv4.z, elv4.w};
#pragma unroll
      for (int h = 0; h < 4; ++h) {
        float x = (elv[h] + erv[h]) * ew_s[et * 4 + h];
        x = (x >= 0.f) ? x : 0.2f * x;
        float M = fmaxf(m[h], x);
        s[h] = s[h] * __expf(m[h] - M) + __expf(x - M);
        m[h] = M;
      }
    }
    // wave combine (butterfly -> all lanes hold global m,s)
#pragma unroll
    for (int off = 1; off < 64; off <<= 1) {
#pragma unroll
      for (int h = 0; h < 4; ++h) {
        float mo = __shfl_xor(m[h], off);
        float so = __shfl_xor(s[h], off);
        float M = fmaxf(m[h], mo);
        s[h] = s[h] * __expf(m[h] - M) + so * __expf(mo - M);
        m[h] = M;
      }
    }
    float rs[4];
#pragma unroll
    for (int h = 0; h < 4; ++h) rs[h] = 1.0f / s[h];
    // pass C: serial over edges, coalesced 256B ft reads per head
    for (int i = 0; i < deg; ++i) {
      int e = ebd[start + i];
      int sv = srcs[e];
      int et = efeats[e] - 1;
      float4 elv4 = *(const float4*)(el + (size_t)sv * 4);
      float elv[4] = {elv4.x, elv4.y, elv4.z, elv4.w};
      const float* fr = ft + (size_t)sv * HD;
#pragma unroll
      for (int h = 0; h < 4; ++h) {
        float x = (elv[h] + erv[h]) * ew_s[et * 4 + h];
        x = (x >= 0.f) ? x : 0.2f * x;
        float w = __expf(x - m[h]) * rs[h];
        acc[h] = fmaf(w, fr[h * DD + lane], acc[h]);
      }
    }
  }
  float* op = out + (size_t)node * HD;
#pragma unroll
  for (int h = 0; h < 4; ++h) op[h * DD + lane] = acc[h];
}

extern "C" void kernel_launch(void* const* d_in, const int* in_sizes, int n_in,
                              void* d_out, int out_size, void* d_ws, size_t ws_size,
                              hipStream_t stream) {
  const float* feat   = (const float*)d_in[0];
  const int*   src    = (const int*)d_in[1];
  const int*   dst    = (const int*)d_in[2];
  const int*   efeats = (const int*)d_in[3];
  const float* fc_w   = (const float*)d_in[4];
  const float* attn_l = (const float*)d_in[5];
  const float* attn_r = (const float*)d_in[6];
  const float* ewt    = (const float*)d_in[7];
  float* out = (float*)d_out;

  int N = in_sizes[0] / NF;   // 50000
  int E = in_sizes[1];        // 800000

  char* ws = (char*)d_ws;
  size_t off = 0;
  float* ft = (float*)(ws + off); off += (size_t)N * HD * 4;        // 51.2 MB
  float* el = (float*)(ws + off); off += (size_t)N * NH * 4;        // 800 KB
  float* er = (float*)(ws + off); off += (size_t)N * NH * 4;        // 800 KB
  int* offs   = (int*)(ws + off); off += ((size_t)N + 16) * 4;      // N+1 (padded)
  int* cursor = (int*)(ws + off); off += (size_t)N * 4;
  int* ebd    = (int*)(ws + off); off += (size_t)E * 4;

  hipMemsetAsync(cursor, 0, (size_t)N * 4, stream);
  hist_k<<<(E + 255) / 256, 256, 0, stream>>>(dst, cursor, E);
  scan_k<<<1, 1024, 0, stream>>>(cursor, offs, N);
  scatter_k<<<(E + 255) / 256, 256, 0, stream>>>(dst, cursor, ebd, E);
  gemm_k<<<(N + 31) / 32, 256, 0, stream>>>(feat, fc_w, attn_l, attn_r, ft, el, er, N);
  agg_k<<<(N + 3) / 4, 256, 0, stream>>>(ft, el, er, src, efeats, ewt, offs, ebd, out, N);
}

// Round 2
// 347.899 us; speedup vs baseline: 1.5123x; 1.5123x over previous
//
#include <hip/hip_runtime.h>

// REGATConv on MI355X — round 2.
//   ws: fcb bf16[256*256] | ftb bf16[N*256] | el[N*4] | er[N*4] | offs[N+1] | cursor[N] | ebd2 int2[E]
//   K1 memset cursor; K2 hist(dst); K3 vectorized single-block scan; K4 scatter (src,etype) by dst
//   K5 cvt fc_w -> bf16
//   K6 MFMA bf16 GEMM (64x256 tile/block, wave=head), fused el/er epilogue, writes ftb bf16
//   K7 one wave per dst node: sum-softmax in registers + ushort4 gather of ftb[src]

#define NF 256
#define HD 256
#define NH 4

typedef __attribute__((ext_vector_type(8))) short short8;
typedef __attribute__((ext_vector_type(4))) float f32x4;

static __device__ __forceinline__ unsigned short f2bf(float f) {
  unsigned int u = __float_as_uint(f);
  u += 0x7FFFu + ((u >> 16) & 1u);   // RNE
  return (unsigned short)(u >> 16);
}
static __device__ __forceinline__ float bf2f(unsigned short s) {
  return __uint_as_float(((unsigned int)s) << 16);
}

__global__ __launch_bounds__(256) void hist_k(const int* __restrict__ dst,
                                              int* __restrict__ cursor, int e) {
  int i = blockIdx.x * 256 + threadIdx.x;
  if (i < e) atomicAdd(&cursor[dst[i]], 1);
}

// single-block scan, 1024 thr x 8 elem -> chunk 8192
__global__ __launch_bounds__(1024) void scan_k(int* __restrict__ cursor,
                                               int* __restrict__ offs, int n) {
  __shared__ int wtot[16];
  __shared__ int wexcl[16];
  __shared__ int ctot;
  int tid = threadIdx.x, lane = tid & 63, wid = tid >> 6;
  int carry = 0;
  int nchunk = (n + 8191) >> 13;
  for (int c = 0; c < nchunk; ++c) {
    int base = (c << 13) + tid * 8;
    int v[8];
    if (base + 8 <= n) {
      int4 a = *(const int4*)(cursor + base);
      int4 b = *(const int4*)(cursor + base + 4);
      v[0] = a.x; v[1] = a.y; v[2] = a.z; v[3] = a.w;
      v[4] = b.x; v[5] = b.y; v[6] = b.z; v[7] = b.w;
    } else {
#pragma unroll
      for (int j = 0; j < 8; ++j) v[j] = (base + j < n) ? cursor[base + j] : 0;
    }
    int p[8]; int run = 0;
#pragma unroll
    for (int j = 0; j < 8; ++j) { run += v[j]; p[j] = run; }
    int incl = run;
#pragma unroll
    for (int off = 1; off < 64; off <<= 1) {
      int t = __shfl_up(incl, off);
      if (lane >= off) incl += t;
    }
    if (lane == 63) wtot[wid] = incl;
    __syncthreads();
    if (wid == 0 && lane < 16) {
      int wv = wtot[lane]; int wi = wv;
#pragma unroll
      for (int off = 1; off < 16; off <<= 1) {
        int t = __shfl_up(wi, off);
        if (lane >= off) wi += t;
      }
      wexcl[lane] = wi - wv;
      if (lane == 15) ctot = wi;
    }
    __syncthreads();
    int ebase = carry + wexcl[wid] + (incl - run);
#pragma unroll
    for (int j = 0; j < 8; ++j) {
      int i = base + j;
      if (i < n) { int ex = ebase + p[j] - v[j]; offs[i] = ex; cursor[i] = ex; }
    }
    carry += ctot;
    __syncthreads();
  }
  if (tid == 0) offs[n] = carry;
}

__global__ __launch_bounds__(256) void scatter_k(const int* __restrict__ src,
                                                 const int* __restrict__ dst,
                                                 const int* __restrict__ efeats,
                                                 int* __restrict__ cursor,
                                                 int2* __restrict__ ebd2, int e) {
  int i = blockIdx.x * 256 + threadIdx.x;
  if (i < e) {
    int p = atomicAdd(&cursor[dst[i]], 1);
    ebd2[p] = make_int2(src[i], efeats[i]);
  }
}

__global__ __launch_bounds__(256) void cvt_k(const float* __restrict__ w,
                                             unsigned short* __restrict__ o) {
  int i = blockIdx.x * 256 + threadIdx.x;   // 16384 threads x float4
  float4 v = ((const float4*)w)[i];
  ushort4 r = make_ushort4(f2bf(v.x), f2bf(v.y), f2bf(v.z), f2bf(v.w));
  ((ushort4*)o)[i] = r;
}

// MFMA GEMM: C[m][o] = sum_k feat[m][k]*fc_w[o][k]. Block: 64 rows x 256 cols,
// 4 waves; wave w owns cols [w*64, w*64+64) == head w. BK=64 (2 mfma k-steps).
// LDS holds fragments in lane-contiguous order -> conflict-free ds_read_b128.
__global__ __launch_bounds__(256) void gemm_k(
    const float* __restrict__ feat, const unsigned short* __restrict__ fcb,
    const float* __restrict__ attn_l, const float* __restrict__ attn_r,
    unsigned short* __restrict__ ftb, float* __restrict__ el,
    float* __restrict__ er, int n) {
  __shared__ short aF[4 * 2 * 64 * 8];    // [rt][s][lane][8]  8 KB
  __shared__ short bF[16 * 2 * 64 * 8];   // [cg][s][lane][8] 32 KB
  int tid = threadIdx.x;
  int lane = tid & 63, w = tid >> 6;
  int row0 = blockIdx.x * 64;

  f32x4 acc[4][4];
#pragma unroll
  for (int i = 0; i < 4; ++i)
#pragma unroll
    for (int j = 0; j < 4; ++j) acc[i][j] = (f32x4){0.f, 0.f, 0.f, 0.f};

  // A staging role: row ar=tid>>2 (0..63), k-chunk ak=(tid&3)*16
  int ar = tid >> 2, ak = (tid & 3) << 4;
  int arow = row0 + ar; if (arow >= n) arow = n - 1;
  const float* ap = feat + (size_t)arow * NF + ak;
  int am = ar & 15, art = ar >> 4;
  int s0 = ak >> 5, q0 = (ak >> 3) & 3;           // first octet
  int s1 = (ak + 8) >> 5, q1 = ((ak + 8) >> 3) & 3;  // second octet
  short* aw0 = &aF[(((art * 2 + s0) * 64) + q0 * 16 + am) * 8];
  short* aw1 = &aF[(((art * 2 + s1) * 64) + q1 * 16 + am) * 8];

  // B staging role: o = tid (0..255), 64 k per slice
  const unsigned short* bp = fcb + (size_t)tid * NF;
  int bn = tid & 15, bcg = tid >> 4;

  for (int k0 = 0; k0 < NF; k0 += 64) {
    float4 f0 = *(const float4*)(ap + k0);
    float4 f1 = *(const float4*)(ap + k0 + 4);
    float4 f2 = *(const float4*)(ap + k0 + 8);
    float4 f3 = *(const float4*)(ap + k0 + 12);
    short8 oa, ob;
    oa[0] = (short)f2bf(f0.x); oa[1] = (short)f2bf(f0.y);
    oa[2] = (short)f2bf(f0.z); oa[3] = (short)f2bf(f0.w);
    oa[4] = (short)f2bf(f1.x); oa[5] = (short)f2bf(f1.y);
    oa[6] = (short)f2bf(f1.z); oa[7] = (short)f2bf(f1.w);
    ob[0] = (short)f2bf(f2.x); ob[1] = (short)f2bf(f2.y);
    ob[2] = (short)f2bf(f2.z); ob[3] = (short)f2bf(f2.w);
    ob[4] = (short)f2bf(f3.x); ob[5] = (short)f2bf(f3.y);
    ob[6] = (short)f2bf(f3.z); ob[7] = (short)f2bf(f3.w);
    *(short8*)aw0 = oa;
    *(short8*)aw1 = ob;
#pragma unroll
    for (int o8 = 0; o8 < 8; ++o8) {
      short8 bv = *(const short8*)(bp + k0 + o8 * 8);
      int bs = o8 >> 2, bq = o8 & 3;
      *(short8*)&bF[(((bcg * 2 + bs) * 64) + bq * 16 + bn) * 8] = bv;
    }
    __syncthreads();
#pragma unroll
    for (int s = 0; s < 2; ++s) {
      short8 af[4], bfr[4];
#pragma unroll
      for (int rt = 0; rt < 4; ++rt)
        af[rt] = *(const short8*)&aF[(((rt * 2 + s) * 64) + lane) * 8];
#pragma unroll
      for (int ct = 0; ct < 4; ++ct)
        bfr[ct] = *(const short8*)&bF[((((w * 4 + ct) * 2 + s) * 64) + lane) * 8];
#pragma unroll
      for (int rt = 0; rt < 4; ++rt)
#pragma unroll
        for (int ct = 0; ct < 4; ++ct)
          acc[rt][ct] = __builtin_amdgcn_mfma_f32_16x16x32_bf16(
              af[rt], bfr[ct], acc[rt][ct], 0, 0, 0);
    }
    __syncthreads();
  }

  // epilogue: wave w == head w. C/D map: col = lane&15, row = (lane>>4)*4 + r.
  int ln = lane & 15, lq = lane >> 4;
  float al4[4], ar4[4];
#pragma unroll
  for (int ct = 0; ct < 4; ++ct) {
    al4[ct] = attn_l[w * 64 + ct * 16 + ln];
    ar4[ct] = attn_r[w * 64 + ct * 16 + ln];
  }
#pragma unroll
  for (int rt = 0; rt < 4; ++rt) {
#pragma unroll
    for (int r = 0; r < 4; ++r) {
      float pl = 0.f, pr = 0.f;
#pragma unroll
      for (int ct = 0; ct < 4; ++ct) {
        float v = acc[rt][ct][r];
        pl += v * al4[ct]; pr += v * ar4[ct];
      }
#pragma unroll
      for (int off = 1; off <= 8; off <<= 1) {
        pl += __shfl_xor(pl, off);
        pr += __shfl_xor(pr, off);
      }
      int row = row0 + rt * 16 + lq * 4 + r;
      if (row < n) {
        if (ln == 0) { el[row * NH + w] = pl; er[row * NH + w] = pr; }
        unsigned short* fr = ftb + (size_t)row * HD + w * 64 + ln;
#pragma unroll
        for (int ct = 0; ct < 4; ++ct) fr[ct * 16] = f2bf(acc[rt][ct][r]);
      }
    }
  }
}

// one wave per dst node; lane owns 4 consecutive output cols o=lane*4..+3
// (head hl=lane>>4). Sum-softmax (no max pass; |logit| bounded).
__global__ __launch_bounds__(256) void agg_k(
    const unsigned short* __restrict__ ftb, const float* __restrict__ el,
    const float* __restrict__ er, const int2* __restrict__ ebd2,
    const float* __restrict__ ewt, const int* __restrict__ offs,
    float* __restrict__ out, int n) {
  __shared__ float ew_s[32];
  if (threadIdx.x < 32) {
    float v = ewt[threadIdx.x] * 100.0f;
    ew_s[threadIdx.x] = (v >= 0.f) ? v : 0.01f * v;
  }
  __syncthreads();
  int node = blockIdx.x * 4 + (threadIdx.x >> 6);
  int lane = threadIdx.x & 63;
  if (node >= n) return;
  int start = offs[node];
  int deg = offs[node + 1] - start;
  float o0 = 0.f, o1 = 0.f, o2 = 0.f, o3 = 0.f;
  if (deg > 0) {
    float4 erv = *(const float4*)(er + (size_t)node * 4);
    float s0 = 0.f, s1 = 0.f, s2 = 0.f, s3 = 0.f;
    for (int i = lane; i < deg; i += 64) {
      int2 e = ebd2[start + i];
      float4 elv = *(const float4*)(el + (size_t)e.x * 4);
      const float* ew = &ew_s[(e.y - 1) * 4];
      float x0 = (elv.x + erv.x) * ew[0]; x0 = (x0 >= 0.f) ? x0 : 0.2f * x0;
      float x1 = (elv.y + erv.y) * ew[1]; x1 = (x1 >= 0.f) ? x1 : 0.2f * x1;
      float x2 = (elv.z + erv.z) * ew[2]; x2 = (x2 >= 0.f) ? x2 : 0.2f * x2;
      float x3 = (elv.w + erv.w) * ew[3]; x3 = (x3 >= 0.f) ? x3 : 0.2f * x3;
      s0 += __expf(x0); s1 += __expf(x1); s2 += __expf(x2); s3 += __expf(x3);
    }
#pragma unroll
    for (int off = 1; off < 64; off <<= 1) {
      s0 += __shfl_xor(s0, off);
      s1 += __shfl_xor(s1, off);
      s2 += __shfl_xor(s2, off);
      s3 += __shfl_xor(s3, off);
    }
    int hl = lane >> 4;
    float erh = (hl == 0) ? erv.x : (hl == 1) ? erv.y : (hl == 2) ? erv.z : erv.w;
    float sh  = (hl == 0) ? s0   : (hl == 1) ? s1   : (hl == 2) ? s2   : s3;
    float rs = 1.0f / sh;
    const float* ewh = &ew_s[hl];
    const unsigned short* fb = ftb + (size_t)lane * 4;
#pragma unroll 2
    for (int i = 0; i < deg; ++i) {
      int2 e = ebd2[start + i];
      float elh = el[(size_t)e.x * 4 + hl];
      float x = (elh + erh) * ewh[(e.y - 1) * 4];
      x = (x >= 0.f) ? x : 0.2f * x;
      float wgt = __expf(x) * rs;
      ushort4 f4 = *(const ushort4*)(fb + (size_t)e.x * HD);
      o0 = fmaf(wgt, bf2f(f4.x), o0);
      o1 = fmaf(wgt, bf2f(f4.y), o1);
      o2 = fmaf(wgt, bf2f(f4.z), o2);
      o3 = fmaf(wgt, bf2f(f4.w), o3);
    }
  }
  *(float4*)(out + (size_t)node * HD + lane * 4) = make_float4(o0, o1, o2, o3);
}

extern "C" void kernel_launch(void* const* d_in, const int* in_sizes, int n_in,
                              void* d_out, int out_size, void* d_ws, size_t ws_size,
                              hipStream_t stream) {
  const float* feat   = (const float*)d_in[0];
  const int*   src    = (const int*)d_in[1];
  const int*   dst    = (const int*)d_in[2];
  const int*   efeats = (const int*)d_in[3];
  const float* fc_w   = (const float*)d_in[4];
  const float* attn_l = (const float*)d_in[5];
  const float* attn_r = (const float*)d_in[6];
  const float* ewt    = (const float*)d_in[7];
  float* out = (float*)d_out;

  int N = in_sizes[0] / NF;   // 50000
  int E = in_sizes[1];        // 800000

  char* ws = (char*)d_ws;
  size_t off = 0;
  unsigned short* fcb = (unsigned short*)(ws + off); off += (size_t)NF * HD * 2;   // 128 KB
  unsigned short* ftb = (unsigned short*)(ws + off); off += (size_t)N * HD * 2;    // 25.6 MB
  float* el  = (float*)(ws + off); off += (size_t)N * NH * 4;
  float* er  = (float*)(ws + off); off += (size_t)N * NH * 4;
  int* offs  = (int*)(ws + off);   off += ((size_t)N + 16) * 4;
  int* cursor = (int*)(ws + off);  off += (size_t)N * 4;
  int2* ebd2 = (int2*)(ws + off);  off += (size_t)E * 8;

  hipMemsetAsync(cursor, 0, (size_t)N * 4, stream);
  hist_k<<<(E + 255) / 256, 256, 0, stream>>>(dst, cursor, E);
  scan_k<<<1, 1024, 0, stream>>>(cursor, offs, N);
  scatter_k<<<(E + 255) / 256, 256, 0, stream>>>(src, dst, efeats, cursor, ebd2, E);
  cvt_k<<<64, 256, 0, stream>>>(fc_w, fcb);
  gemm_k<<<(N + 63) / 64, 256, 0, stream>>>(feat, fcb, attn_l, attn_r, ftb, el, er, N);
  agg_k<<<(N + 3) / 4, 256, 0, stream>>>(ftb, el, er, ebd2, ewt, offs, out, N);
}

// Round 4
// 331.899 us; speedup vs baseline: 1.5852x; 1.0482x over previous
//
#include <hip/hip_runtime.h>
#include <hip/hip_bf16.h>

// REGATConv on MI355X — round 3 (resubmit after infra failure).
//   ws: fcb bf16[256*256] | ftb bf16[N*256] | el[N*4] | er[N*4] | offs[N+1] | cursor[N]
//       | srcs_g int[E] | exq float4[E]
//   K1 memset cursor; K2 hist(dst); K3 single-block scan
//   K4 cvt fc_w -> bf16
//   K5 MFMA bf16 GEMM (64x256 tile, wave=head), fused el/er epilogue, writes ftb bf16
//   K6 scatter2: group edges by dst AND precompute exq = exp(leaky((el+er)*ew)) per head
//   K7 agg2: one wave per dst node: sequential exq sum -> rs, then 4x-unrolled ftb gather

#define NF 256
#define HD 256
#define NH 4

typedef __attribute__((ext_vector_type(8))) short short8;
typedef __attribute__((ext_vector_type(4))) float f32x4;

static __device__ __forceinline__ unsigned short f2bf(float f) {
  unsigned int u = __float_as_uint(f);
  u += 0x7FFFu + ((u >> 16) & 1u);   // RNE
  return (unsigned short)(u >> 16);
}
static __device__ __forceinline__ float bf2f(unsigned short s) {
  return __uint_as_float(((unsigned int)s) << 16);
}
static __device__ __forceinline__ unsigned pkbf(float a, float b) {
  __hip_bfloat162 h = __float22bfloat162_rn(make_float2(a, b));
  return *(unsigned*)&h;   // low short = a, high short = b
}

__global__ __launch_bounds__(256) void hist_k(const int* __restrict__ dst,
                                              int* __restrict__ cursor, int e) {
  int i = blockIdx.x * 256 + threadIdx.x;
  if (i < e) atomicAdd(&cursor[dst[i]], 1);
}

// single-block scan, 1024 thr x 8 elem -> chunk 8192
__global__ __launch_bounds__(1024) void scan_k(int* __restrict__ cursor,
                                               int* __restrict__ offs, int n) {
  __shared__ int wtot[16];
  __shared__ int wexcl[16];
  __shared__ int ctot;
  int tid = threadIdx.x, lane = tid & 63, wid = tid >> 6;
  int carry = 0;
  int nchunk = (n + 8191) >> 13;
  for (int c = 0; c < nchunk; ++c) {
    int base = (c << 13) + tid * 8;
    int v[8];
    if (base + 8 <= n) {
      int4 a = *(const int4*)(cursor + base);
      int4 b = *(const int4*)(cursor + base + 4);
      v[0] = a.x; v[1] = a.y; v[2] = a.z; v[3] = a.w;
      v[4] = b.x; v[5] = b.y; v[6] = b.z; v[7] = b.w;
    } else {
#pragma unroll
      for (int j = 0; j < 8; ++j) v[j] = (base + j < n) ? cursor[base + j] : 0;
    }
    int p[8]; int run = 0;
#pragma unroll
    for (int j = 0; j < 8; ++j) { run += v[j]; p[j] = run; }
    int incl = run;
#pragma unroll
    for (int off = 1; off < 64; off <<= 1) {
      int t = __shfl_up(incl, off);
      if (lane >= off) incl += t;
    }
    if (lane == 63) wtot[wid] = incl;
    __syncthreads();
    if (wid == 0 && lane < 16) {
      int wv = wtot[lane]; int wi = wv;
#pragma unroll
      for (int off = 1; off < 16; off <<= 1) {
        int t = __shfl_up(wi, off);
        if (lane >= off) wi += t;
      }
      wexcl[lane] = wi - wv;
      if (lane == 15) ctot = wi;
    }
    __syncthreads();
    int ebase = carry + wexcl[wid] + (incl - run);
#pragma unroll
    for (int j = 0; j < 8; ++j) {
      int i = base + j;
      if (i < n) { int ex = ebase + p[j] - v[j]; offs[i] = ex; cursor[i] = ex; }
    }
    carry += ctot;
    __syncthreads();
  }
  if (tid == 0) offs[n] = carry;
}

__global__ __launch_bounds__(256) void cvt_k(const float* __restrict__ w,
                                             unsigned short* __restrict__ o) {
  int i = blockIdx.x * 256 + threadIdx.x;   // 16384 threads x float4
  float4 v = ((const float4*)w)[i];
  uint2 r = make_uint2(pkbf(v.x, v.y), pkbf(v.z, v.w));
  ((uint2*)o)[i] = r;
}

// MFMA GEMM: C[m][o] = sum_k feat[m][k]*fc_w[o][k]. Block: 64 rows x 256 cols,
// 4 waves; wave w owns cols [w*64, w*64+64) == head w. BK=64 (2 mfma k-steps).
__global__ __launch_bounds__(256) void gemm_k(
    const float* __restrict__ feat, const unsigned short* __restrict__ fcb,
    const float* __restrict__ attn_l, const float* __restrict__ attn_r,
    unsigned short* __restrict__ ftb, float* __restrict__ el,
    float* __restrict__ er, int n) {
  __shared__ short aF[4 * 2 * 64 * 8];    // [rt][s][lane][8]  8 KB
  __shared__ short bF[16 * 2 * 64 * 8];   // [cg][s][lane][8] 32 KB
  int tid = threadIdx.x;
  int lane = tid & 63, w = tid >> 6;
  int row0 = blockIdx.x * 64;

  f32x4 acc[4][4];
#pragma unroll
  for (int i = 0; i < 4; ++i)
#pragma unroll
    for (int j = 0; j < 4; ++j) acc[i][j] = (f32x4){0.f, 0.f, 0.f, 0.f};

  // A staging role: row ar=tid>>2 (0..63), k-chunk ak=(tid&3)*16
  int ar = tid >> 2, ak = (tid & 3) << 4;
  int arow = row0 + ar; if (arow >= n) arow = n - 1;
  const float* ap = feat + (size_t)arow * NF + ak;
  int am = ar & 15, art = ar >> 4;
  int s0 = ak >> 5, q0 = (ak >> 3) & 3;               // first octet
  int s1 = (ak + 8) >> 5, q1 = ((ak + 8) >> 3) & 3;   // second octet
  short* aw0 = &aF[(((art * 2 + s0) * 64) + q0 * 16 + am) * 8];
  short* aw1 = &aF[(((art * 2 + s1) * 64) + q1 * 16 + am) * 8];

  // B staging role: o = tid (0..255), 64 k per slice
  const unsigned short* bp = fcb + (size_t)tid * NF;
  int bn = tid & 15, bcg = tid >> 4;

  for (int k0 = 0; k0 < NF; k0 += 64) {
    float4 f0 = *(const float4*)(ap + k0);
    float4 f1 = *(const float4*)(ap + k0 + 4);
    float4 f2 = *(const float4*)(ap + k0 + 8);
    float4 f3 = *(const float4*)(ap + k0 + 12);
    uint4 oa = make_uint4(pkbf(f0.x, f0.y), pkbf(f0.z, f0.w),
                          pkbf(f1.x, f1.y), pkbf(f1.z, f1.w));
    uint4 ob = make_uint4(pkbf(f2.x, f2.y), pkbf(f2.z, f2.w),
                          pkbf(f3.x, f3.y), pkbf(f3.z, f3.w));
    *(uint4*)aw0 = oa;
    *(uint4*)aw1 = ob;
#pragma unroll
    for (int o8 = 0; o8 < 8; ++o8) {
      short8 bv = *(const short8*)(bp + k0 + o8 * 8);
      int bs = o8 >> 2, bq = o8 & 3;
      *(short8*)&bF[(((bcg * 2 + bs) * 64) + bq * 16 + bn) * 8] = bv;
    }
    __syncthreads();
#pragma unroll
    for (int s = 0; s < 2; ++s) {
      short8 af[4], bfr[4];
#pragma unroll
      for (int rt = 0; rt < 4; ++rt)
        af[rt] = *(const short8*)&aF[(((rt * 2 + s) * 64) + lane) * 8];
#pragma unroll
      for (int ct = 0; ct < 4; ++ct)
        bfr[ct] = *(const short8*)&bF[((((w * 4 + ct) * 2 + s) * 64) + lane) * 8];
#pragma unroll
      for (int rt = 0; rt < 4; ++rt)
#pragma unroll
        for (int ct = 0; ct < 4; ++ct)
          acc[rt][ct] = __builtin_amdgcn_mfma_f32_16x16x32_bf16(
              af[rt], bfr[ct], acc[rt][ct], 0, 0, 0);
    }
    __syncthreads();
  }

  // epilogue: wave w == head w. C/D map: col = lane&15, row = (lane>>4)*4 + r.
  int ln = lane & 15, lq = lane >> 4;
  float al4[4], ar4[4];
#pragma unroll
  for (int ct = 0; ct < 4; ++ct) {
    al4[ct] = attn_l[w * 64 + ct * 16 + ln];
    ar4[ct] = attn_r[w * 64 + ct * 16 + ln];
  }
#pragma unroll
  for (int rt = 0; rt < 4; ++rt) {
#pragma unroll
    for (int r = 0; r < 4; ++r) {
      float pl = 0.f, pr = 0.f;
#pragma unroll
      for (int ct = 0; ct < 4; ++ct) {
        float v = acc[rt][ct][r];
        pl += v * al4[ct]; pr += v * ar4[ct];
      }
#pragma unroll
      for (int off = 1; off <= 8; off <<= 1) {
        pl += __shfl_xor(pl, off);
        pr += __shfl_xor(pr, off);
      }
      int row = row0 + rt * 16 + lq * 4 + r;
      if (row < n) {
        if (ln == 0) { el[row * NH + w] = pl; er[row * NH + w] = pr; }
        unsigned short* fr = ftb + (size_t)row * HD + w * 64 + ln;
#pragma unroll
        for (int ct = 0; ct < 4; ++ct) fr[ct * 16] = f2bf(acc[rt][ct][r]);
      }
    }
  }
}

// group edges by dst AND precompute per-edge, per-head exp(leaky((el+er)*ew))
__global__ __launch_bounds__(256) void scatter2_k(
    const int* __restrict__ src, const int* __restrict__ dst,
    const int* __restrict__ efeats, const float* __restrict__ el,
    const float* __restrict__ er, const float* __restrict__ ewt,
    int* __restrict__ cursor, int* __restrict__ srcs_g,
    float4* __restrict__ exq, int e) {
  __shared__ float ew_s[32];
  if (threadIdx.x < 32) {
    float v = ewt[threadIdx.x] * 100.0f;
    ew_s[threadIdx.x] = (v >= 0.f) ? v : 0.01f * v;
  }
  __syncthreads();
  int i = blockIdx.x * 256 + threadIdx.x;
  if (i >= e) return;
  int d = dst[i], s = src[i], t = efeats[i] - 1;
  int p = atomicAdd(&cursor[d], 1);
  float4 elv = *(const float4*)(el + (size_t)s * 4);
  float4 erv = *(const float4*)(er + (size_t)d * 4);
  const float* ew = &ew_s[t * 4];
  float x0 = (elv.x + erv.x) * ew[0]; x0 = (x0 >= 0.f) ? x0 : 0.2f * x0;
  float x1 = (elv.y + erv.y) * ew[1]; x1 = (x1 >= 0.f) ? x1 : 0.2f * x1;
  float x2 = (elv.z + erv.z) * ew[2]; x2 = (x2 >= 0.f) ? x2 : 0.2f * x2;
  float x3 = (elv.w + erv.w) * ew[3]; x3 = (x3 >= 0.f) ? x3 : 0.2f * x3;
  exq[p] = make_float4(__expf(x0), __expf(x1), __expf(x2), __expf(x3));
  srcs_g[p] = s;
}

// one wave per dst node; lane owns output cols lane*4..lane*4+3 (head hl=lane>>4).
__global__ __launch_bounds__(256) void agg2_k(
    const unsigned short* __restrict__ ftb, const int* __restrict__ srcs_g,
    const float4* __restrict__ exq, const int* __restrict__ offs,
    float* __restrict__ out, int n) {
  int node = blockIdx.x * 4 + (threadIdx.x >> 6);
  int lane = threadIdx.x & 63;
  if (node >= n) return;
  int start = offs[node];
  int deg = offs[node + 1] - start;
  float o0 = 0.f, o1 = 0.f, o2 = 0.f, o3 = 0.f;
  if (deg > 0) {
    // pass A: sequential sum of exq over the group (coalesced float4 loads)
    float s0 = 0.f, s1 = 0.f, s2 = 0.f, s3 = 0.f;
    for (int i = lane; i < deg; i += 64) {
      float4 q = exq[(size_t)start + i];
      s0 += q.x; s1 += q.y; s2 += q.z; s3 += q.w;
    }
#pragma unroll
    for (int off = 1; off < 64; off <<= 1) {
      s0 += __shfl_xor(s0, off);
      s1 += __shfl_xor(s1, off);
      s2 += __shfl_xor(s2, off);
      s3 += __shfl_xor(s3, off);
    }
    int hl = lane >> 4;
    float sh = (hl == 0) ? s0 : (hl == 1) ? s1 : (hl == 2) ? s2 : s3;
    float rs = 1.0f / sh;
    // pass C: 4x-unrolled gather (4 outstanding 8B loads/lane)
    const float* exs = (const float*)exq;
    const unsigned short* fb = ftb + (size_t)lane * 4;
    const int* sg = srcs_g + start;
    long b4 = (long)start * 4 + hl;
    int i = 0;
    for (; i + 4 <= deg; i += 4) {
      int sA = sg[i], sB = sg[i + 1], sC = sg[i + 2], sD = sg[i + 3];
      float wA = exs[b4 + (long)i * 4] * rs;
      float wB = exs[b4 + (long)(i + 1) * 4] * rs;
      float wC = exs[b4 + (long)(i + 2) * 4] * rs;
      float wD = exs[b4 + (long)(i + 3) * 4] * rs;
      ushort4 fA = *(const ushort4*)(fb + (size_t)sA * HD);
      ushort4 fB = *(const ushort4*)(fb + (size_t)sB * HD);
      ushort4 fC = *(const ushort4*)(fb + (size_t)sC * HD);
      ushort4 fD = *(const ushort4*)(fb + (size_t)sD * HD);
      o0 = fmaf(wA, bf2f(fA.x), o0); o1 = fmaf(wA, bf2f(fA.y), o1);
      o2 = fmaf(wA, bf2f(fA.z), o2); o3 = fmaf(wA, bf2f(fA.w), o3);
      o0 = fmaf(wB, bf2f(fB.x), o0); o1 = fmaf(wB, bf2f(fB.y), o1);
      o2 = fmaf(wB, bf2f(fB.z), o2); o3 = fmaf(wB, bf2f(fB.w), o3);
      o0 = fmaf(wC, bf2f(fC.x), o0); o1 = fmaf(wC, bf2f(fC.y), o1);
      o2 = fmaf(wC, bf2f(fC.z), o2); o3 = fmaf(wC, bf2f(fC.w), o3);
      o0 = fmaf(wD, bf2f(fD.x), o0); o1 = fmaf(wD, bf2f(fD.y), o1);
      o2 = fmaf(wD, bf2f(fD.z), o2); o3 = fmaf(wD, bf2f(fD.w), o3);
    }
    for (; i < deg; ++i) {
      int sA = sg[i];
      float wA = exs[b4 + (long)i * 4] * rs;
      ushort4 fA = *(const ushort4*)(fb + (size_t)sA * HD);
      o0 = fmaf(wA, bf2f(fA.x), o0); o1 = fmaf(wA, bf2f(fA.y), o1);
      o2 = fmaf(wA, bf2f(fA.z), o2); o3 = fmaf(wA, bf2f(fA.w), o3);
    }
  }
  *(float4*)(out + (size_t)node * HD + lane * 4) = make_float4(o0, o1, o2, o3);
}

extern "C" void kernel_launch(void* const* d_in, const int* in_sizes, int n_in,
                              void* d_out, int out_size, void* d_ws, size_t ws_size,
                              hipStream_t stream) {
  const float* feat   = (const float*)d_in[0];
  const int*   src    = (const int*)d_in[1];
  const int*   dst    = (const int*)d_in[2];
  const int*   efeats = (const int*)d_in[3];
  const float* fc_w   = (const float*)d_in[4];
  const float* attn_l = (const float*)d_in[5];
  const float* attn_r = (const float*)d_in[6];
  const float* ewt    = (const float*)d_in[7];
  float* out = (float*)d_out;

  int N = in_sizes[0] / NF;   // 50000
  int E = in_sizes[1];        // 800000

  char* ws = (char*)d_ws;
  size_t off = 0;
  unsigned short* fcb = (unsigned short*)(ws + off); off += (size_t)NF * HD * 2;  // 128 KB
  unsigned short* ftb = (unsigned short*)(ws + off); off += (size_t)N * HD * 2;   // 25.6 MB
  float* el  = (float*)(ws + off);  off += (size_t)N * NH * 4;
  float* er  = (float*)(ws + off);  off += (size_t)N * NH * 4;
  int* offs  = (int*)(ws + off);    off += ((size_t)N + 16) * 4;
  int* cursor = (int*)(ws + off);   off += (size_t)N * 4;
  int* srcs_g = (int*)(ws + off);   off += (size_t)E * 4;
  float4* exq = (float4*)(ws + off); off += (size_t)E * 16;

  hipMemsetAsync(cursor, 0, (size_t)N * 4, stream);
  hist_k<<<(E + 255) / 256, 256, 0, stream>>>(dst, cursor, E);
  scan_k<<<1, 1024, 0, stream>>>(cursor, offs, N);
  cvt_k<<<64, 256, 0, stream>>>(fc_w, fcb);
  gemm_k<<<(N + 63) / 64, 256, 0, stream>>>(feat, fcb, attn_l, attn_r, ftb, el, er, N);
  scatter2_k<<<(E + 255) / 256, 256, 0, stream>>>(src, dst, efeats, el, er, ewt,
                                                  cursor, srcs_g, exq, E);
  agg2_k<<<(N + 3) / 4, 256, 0, stream>>>(ftb, srcs_g, exq, offs, out, N);
}